// Round 2
// baseline (453.694 us; speedup 1.0000x reference)
//
#include <hip/hip_runtime.h>
#include <math.h>

// Problem constants (from reference setup_inputs)
constexpr int N  = 8;
constexpr int C  = 32;
constexpr int H  = 256;
constexpr int W  = 256;
constexpr int HU = 512;   // upsampled H
constexpr int WU = 512;   // upsampled W

// Output tile per 256-thread block: 64 wide x 4 high. Wave = 64x1 strip so
// each vector load's lanes touch one input row (locality fix, round 1:
// FETCH_SIZE halved). Round 2: explicit 4-deep channel pipeline to fix the
// measured MLP~1 serialization (VGPR=32, VALUBusy 20%, latency-bound).
constexpr int TX = 64;
constexpr int TY = 4;
constexpr int PF = 4;     // channel-pipeline depth: 12 x4-loads in flight/wave

// Under-aligned float4: one global_load_dwordx4 per 3-tap stencil row
// (dword-aligned dwordx4 is legal on gfx950; spare lane discarded).
typedef float f4 __attribute__((ext_vector_type(4)));
typedef f4 f4u __attribute__((aligned(4)));

// Per-axis decomposition of (grid_sample bilinear) o (upsample2x bilinear):
// a continuous coordinate into the virtual upsampled axis collapses to a
// 3-consecutive-texel window of the ORIGINAL axis with 3 merged weights.
struct Axis {
    int   base;          // window base in original axis, in [0, n_in-3]
    float w0, w1, w2;    // weights for base, base+1, base+2
};

__device__ __forceinline__ Axis make_axis(float coord, int n_in, int n_up) {
    float c0f = floorf(coord);
    float t   = coord - c0f;         // grid_sample frac weight
    int   u0  = (int)c0f;            // upsampled-axis corner a

    float w3_0 = 0.f, w3_1 = 0.f, w3_2 = 0.f;
    int rb = 0;

    #pragma unroll
    for (int k = 0; k < 2; ++k) {
        int   yu    = u0 + k;
        float Wc    = (k == 0) ? (1.0f - t) : t;      // grid_sample corner weight
        bool  valid = (yu >= 0) && (yu < n_up);       // zero-padding mask

        // upsample2x source: s = (yu+0.5)/2 - 0.5, clamped >= 0
        float s  = fmaxf(0.5f * (float)yu - 0.25f, 0.0f);
        int   r0 = (int)s;                            // floor (s >= 0)
        r0 = min(r0, n_in - 1);                       // keep in-bounds for wild yu
        float wu = s - (float)r0;
        int   r1 = min(r0 + 1, n_in - 1);

        float w0 = valid ? Wc * (1.0f - wu) : 0.0f;
        float w1 = valid ? Wc * wu          : 0.0f;

        if (k == 0) rb = min(r0, n_in - 3);           // window base from corner a

        int s0 = min(max(r0 - rb, 0), 2);
        int s1 = min(max(r1 - rb, 0), 2);
        // branchless scatter into 3 slots (keeps everything in registers)
        w3_0 += (s0 == 0) ? w0 : 0.0f;
        w3_1 += (s0 == 1) ? w0 : 0.0f;
        w3_2 += (s0 == 2) ? w0 : 0.0f;
        w3_0 += (s1 == 0) ? w1 : 0.0f;
        w3_1 += (s1 == 1) ? w1 : 0.0f;
        w3_2 += (s1 == 2) ? w1 : 0.0f;
    }

    Axis ax;
    ax.base = rb;
    ax.w0 = w3_0; ax.w1 = w3_1; ax.w2 = w3_2;
    return ax;
}

__global__ __launch_bounds__(256)
void fused_up_affine_sample(const float* __restrict__ x,
                            const float* __restrict__ theta,
                            float* __restrict__ out) {
    int lane = threadIdx.x & 63;          // position within wave
    int wv   = threadIdx.x >> 6;          // wave id within block
    int wo = blockIdx.x * TX + lane;      // output col (wave = 64x1 strip)
    int ho = blockIdx.y * TY + wv;        // output row
    int n  = blockIdx.z;                  // block-uniform -> SGPR theta

    // affine grid (reference: xs=(2w+1)/W-1, ys=(2h+1)/H-1)
    float gx = (2.0f * (float)wo + 1.0f) * (1.0f / (float)WU) - 1.0f;
    float gy = (2.0f * (float)ho + 1.0f) * (1.0f / (float)HU) - 1.0f;

    const float* th = theta + n * 6;
    float ox = th[0] * gx + th[1] * gy + th[2];
    float oy = th[3] * gx + th[4] * gy + th[5];

    // grid_sample continuous coords into the (virtual) upsampled image
    float ix = ((ox + 1.0f) * (float)WU - 1.0f) * 0.5f;
    float iy = ((oy + 1.0f) * (float)HU - 1.0f) * 0.5f;

    Axis axx = make_axis(ix, W, WU);
    Axis axy = make_axis(iy, H, HU);

    const float* xb = x   + (size_t)n * (C * H * W);
    float*       ob = out + (size_t)n * (C * HU * WU);
    int loff = axy.base * W + axx.base;   // per-lane load offset (elements)
    int soff = ho * WU + wo;              // per-lane store offset

    float hw0 = axx.w0, hw1 = axx.w1, hw2 = axx.w2;
    float vw0 = axy.w0, vw1 = axy.w1, vw2 = axy.w2;

    // Channel pipeline ring. All indexing is compile-time constant after the
    // full unrolls below (rule: runtime-indexed ext_vector arrays -> scratch).
    f4 ra[PF], rb[PF], rd[PF];

    // Issue the 3 row loads for channel c into ring slot s.
    // Last channel uses a window shifted left by one element (consume
    // .y/.z/.w instead of .x/.y/.z) so the 16B read's last byte lands exactly
    // on element (c+1)*H*W - 1 of this image — never past the allocation.
    auto issue = [&](int s, int c) {
        const float* p = xb + c * (H * W) + loff - ((c == C - 1) ? 1 : 0);
        ra[s] = *(const f4u*)(p);
        rb[s] = *(const f4u*)(p + W);
        rd[s] = *(const f4u*)(p + 2 * W);
    };

    #pragma unroll
    for (int i = 0; i < PF; ++i) issue(i, i);   // prologue: channels 0..PF-1

    #pragma unroll
    for (int c = 0; c < C; ++c) {
        int s = c % PF;                          // constant after unroll
        f4 a = ra[s];
        f4 b = rb[s];
        f4 d = rd[s];
        if (c + PF < C) issue(s, c + PF);        // refill slot before compute

        float r0, r1, r2;
        if (c == C - 1) {                        // shifted-window components
            r0 = a.y * hw0 + a.z * hw1 + a.w * hw2;
            r1 = b.y * hw0 + b.z * hw1 + b.w * hw2;
            r2 = d.y * hw0 + d.z * hw1 + d.w * hw2;
        } else {
            r0 = a.x * hw0 + a.y * hw1 + a.z * hw2;
            r1 = b.x * hw0 + b.y * hw1 + b.z * hw2;
            r2 = d.x * hw0 + d.y * hw1 + d.z * hw2;
        }
        ob[c * (HU * WU) + soff] = vw0 * r0 + vw1 * r1 + vw2 * r2;
    }
}

extern "C" void kernel_launch(void* const* d_in, const int* in_sizes, int n_in,
                              void* d_out, int out_size, void* d_ws, size_t ws_size,
                              hipStream_t stream) {
    const float* x     = (const float*)d_in[0];
    const float* theta = (const float*)d_in[1];
    float*       out   = (float*)d_out;

    dim3 grid(WU / TX, HU / TY, N);   // 8 x 128 x 8 = 8192 blocks
    fused_up_affine_sample<<<grid, 256, 0, stream>>>(x, theta, out);
}

// Round 3
// 403.809 us; speedup vs baseline: 1.1235x; 1.1235x over previous
//
#include <hip/hip_runtime.h>
#include <math.h>

// Problem constants (from reference setup_inputs)
constexpr int N  = 8;
constexpr int C  = 32;
constexpr int H  = 256;
constexpr int W  = 256;
constexpr int HU = 512;   // upsampled H
constexpr int WU = 512;   // upsampled W
constexpr int HW = H * W;

// Round-3 structure: each lane produces a 2x2 OUTPUT QUAD from one shared
// 4x4 input window (4 dwordx4 row loads, every byte used). Rationale: rocprof
// shows the kernel is VMEM-pipe-occupancy bound (one 64-out iteration retires
// per ~125 CU-cycles ~= the TA/TCP cost of 3 divergent dwordx4 + 1 store;
// VALU 17%, HBM 18%, occupancy 76%). Compiler refuses to pipeline loads
// (round 2: VGPR stayed 32), so the fix is FEWER gather instructions per
// output: 3 -> 1 load, 1 -> 0.5 store.
typedef float f4 __attribute__((ext_vector_type(4)));
typedef float f2 __attribute__((ext_vector_type(2)));
typedef f4 f4u __attribute__((aligned(4)));   // dword-aligned dwordx4 load

// Per-axis decomposition of (grid_sample bilinear) o (upsample2x bilinear):
// a continuous coordinate collapses to a 3-consecutive-texel window of the
// ORIGINAL axis with 3 merged weights. base clamped to [0, n_in-3].
struct Axis {
    int   base;
    float w0, w1, w2;
};

__device__ __forceinline__ Axis make_axis(float coord, int n_in, int n_up) {
    float c0f = floorf(coord);
    float t   = coord - c0f;         // grid_sample frac weight
    int   u0  = (int)c0f;            // upsampled-axis corner a

    float w3_0 = 0.f, w3_1 = 0.f, w3_2 = 0.f;
    int rb = 0;

    #pragma unroll
    for (int k = 0; k < 2; ++k) {
        int   yu    = u0 + k;
        float Wc    = (k == 0) ? (1.0f - t) : t;      // grid_sample corner weight
        bool  valid = (yu >= 0) && (yu < n_up);       // zero-padding mask

        // upsample2x source: s = (yu+0.5)/2 - 0.5, clamped >= 0
        float s  = fmaxf(0.5f * (float)yu - 0.25f, 0.0f);
        int   r0 = (int)s;                            // floor (s >= 0)
        r0 = min(r0, n_in - 1);                       // keep in-bounds for wild yu
        float wu = s - (float)r0;
        int   r1 = min(r0 + 1, n_in - 1);

        float w0 = valid ? Wc * (1.0f - wu) : 0.0f;
        float w1 = valid ? Wc * wu          : 0.0f;

        if (k == 0) rb = min(r0, n_in - 3);           // window base from corner a

        int s0 = min(max(r0 - rb, 0), 2);
        int s1 = min(max(r1 - rb, 0), 2);
        w3_0 += (s0 == 0) ? w0 : 0.0f;
        w3_1 += (s0 == 1) ? w0 : 0.0f;
        w3_2 += (s0 == 2) ? w0 : 0.0f;
        w3_0 += (s1 == 0) ? w1 : 0.0f;
        w3_1 += (s1 == 1) ? w1 : 0.0f;
        w3_2 += (s1 == 2) ? w1 : 0.0f;
    }

    Axis ax;
    ax.base = rb;
    ax.w0 = w3_0; ax.w1 = w3_1; ax.w2 = w3_2;
    return ax;
}

// 4-wide weight vector aligned to the shared window: e = base - bl in {0,1}.
__device__ __forceinline__ f4 wvec(const Axis& a, int bl) {
    int e = a.base - bl;
    return e ? f4{0.0f, a.w0, a.w1, a.w2} : f4{a.w0, a.w1, a.w2, 0.0f};
}

__global__ __launch_bounds__(128, 4)
void fused_up_affine_sample(const float* __restrict__ x,
                            const float* __restrict__ theta,
                            float* __restrict__ out) {
    int tid  = threadIdx.x;
    int lane = tid & 63;
    int wv   = tid >> 6;                     // wave id in block (0..1)
    int lx   = lane & 31;                    // col-pair index within wave
    int ly   = lane >> 5;                    // row-pair index within wave

    int wo = blockIdx.x * 64 + lx * 2;       // output cols wo, wo+1
    int ho = blockIdx.y * 8 + wv * 4 + ly * 2; // output rows ho, ho+1
    int n  = blockIdx.z;

    const float* th = theta + n * 6;
    float t0 = th[0], t1 = th[1], t2 = th[2];
    float t3 = th[3], t4 = th[4], t5 = th[5];

    // Axes for the 4 quad pixels (ix AND iy both depend on col and row).
    Axis x00, y00, x01, y01, x10, y10, x11, y11;
    auto pix = [&](int wo_, int ho_, Axis& axx, Axis& axy) {
        float gx = (2.0f * (float)wo_ + 1.0f) * (1.0f / (float)WU) - 1.0f;
        float gy = (2.0f * (float)ho_ + 1.0f) * (1.0f / (float)HU) - 1.0f;
        float ox = t0 * gx + t1 * gy + t2;
        float oy = t3 * gx + t4 * gy + t5;
        float ix = ((ox + 1.0f) * (float)WU - 1.0f) * 0.5f;
        float iy = ((oy + 1.0f) * (float)HU - 1.0f) * 0.5f;
        axx = make_axis(ix, W, WU);
        axy = make_axis(iy, H, HU);
    };
    pix(wo,     ho,     x00, y00);
    pix(wo + 1, ho,     x01, y01);
    pix(wo,     ho + 1, x10, y10);
    pix(wo + 1, ho + 1, x11, y11);

    int bminx = min(min(x00.base, x01.base), min(x10.base, x11.base));
    int bmaxx = max(max(x00.base, x01.base), max(x10.base, x11.base));
    int bminy = min(min(y00.base, y01.base), min(y10.base, y11.base));
    int bmaxy = max(max(y00.base, y01.base), max(y10.base, y11.base));
    bool ok = (bmaxx - bminx <= 1) && (bmaxy - bminy <= 1);

    const float* xb = x   + (size_t)n * (C * HW);
    float*       ob = out + (size_t)n * (C * HU * WU);

    if (!__any(!ok)) {
        // ---- fast path: one 4x4 window serves the whole quad ----
        // Clamp union base so rows/cols bl..bl+3 are always in-image. When
        // bmin==n-3 the clamp shifts by 1; then all pixel bases == bmin, so
        // e = base-bl stays in {0,1} and weight slot 3 gets the zero weight.
        int blx = min(bminx, W - 4);
        int bly = min(bminy, H - 4);

        f4 wx00 = wvec(x00, blx), wx01 = wvec(x01, blx);
        f4 wx10 = wvec(x10, blx), wx11 = wvec(x11, blx);
        f4 wy00 = wvec(y00, bly), wy01 = wvec(y01, bly);
        f4 wy10 = wvec(y10, bly), wy11 = wvec(y11, bly);

        int loff = bly * W + blx;            // per-lane load offset (elements)
        int soff = ho * WU + wo;             // per-lane store offset

        #pragma unroll 4
        for (int c = 0; c < C; ++c) {
            const float* p = xb + c * HW + loff;
            f4 a0 = *(const f4u*)(p);
            f4 a1 = *(const f4u*)(p + W);
            f4 a2 = *(const f4u*)(p + 2 * W);
            f4 a3 = *(const f4u*)(p + 3 * W);

            auto pxv = [&](const f4& wy, const f4& wx) -> float {
                f4 acc = a0 * wy.x + a1 * wy.y + a2 * wy.z + a3 * wy.w;
                return acc.x * wx.x + acc.y * wx.y + acc.z * wx.z + acc.w * wx.w;
            };
            float o00 = pxv(wy00, wx00);
            float o01 = pxv(wy01, wx01);
            float o10 = pxv(wy10, wx10);
            float o11 = pxv(wy11, wx11);

            float* po = ob + c * (HU * WU) + soff;
            *(f2*)(po)      = f2{o00, o01};
            *(f2*)(po + WU) = f2{o10, o11};
        }
    } else {
        // ---- rare fallback (extreme theta): per-pixel 3x3 scalar gather ----
        #pragma unroll
        for (int i = 0; i < 4; ++i) {
            Axis axx = (i == 0) ? x00 : (i == 1) ? x01 : (i == 2) ? x10 : x11;
            Axis axy = (i == 0) ? y00 : (i == 1) ? y01 : (i == 2) ? y10 : y11;
            int wo_ = wo + (i & 1);
            int ho_ = ho + (i >> 1);
            const float* pb = xb + axy.base * W + axx.base;
            float*       po = ob + ho_ * WU + wo_;
            for (int c = 0; c < C; ++c) {
                const float* p = pb + c * HW;
                float r0 = p[0        ] * axx.w0 + p[1        ] * axx.w1 + p[2        ] * axx.w2;
                float r1 = p[W        ] * axx.w0 + p[W + 1    ] * axx.w1 + p[W + 2    ] * axx.w2;
                float r2 = p[2 * W    ] * axx.w0 + p[2 * W + 1] * axx.w1 + p[2 * W + 2] * axx.w2;
                po[c * (HU * WU)] = axy.w0 * r0 + axy.w1 * r1 + axy.w2 * r2;
            }
        }
    }
}

extern "C" void kernel_launch(void* const* d_in, const int* in_sizes, int n_in,
                              void* d_out, int out_size, void* d_ws, size_t ws_size,
                              hipStream_t stream) {
    const float* x     = (const float*)d_in[0];
    const float* theta = (const float*)d_in[1];
    float*       out   = (float*)d_out;

    dim3 grid(WU / 64, HU / 8, N);   // 8 x 64 x 8 = 4096 blocks, 128 thr
    fused_up_affine_sample<<<grid, 128, 0, stream>>>(x, theta, out);
}